// Round 6
// baseline (569.697 us; speedup 1.0000x reference)
//
#include <hip/hip_runtime.h>
#include <hip/hip_bf16.h>

typedef short bf16x8 __attribute__((ext_vector_type(8)));
typedef float f32x4 __attribute__((ext_vector_type(4)));

__device__ __forceinline__ unsigned short f2bf(float f) {
  union { float f; unsigned int u; } x; x.f = f;
  return (unsigned short)((x.u + 0x7fffu + ((x.u >> 16) & 1u)) >> 16);
}
__device__ __forceinline__ float bf2f(unsigned short u) {
  union { unsigned int u; float f; } x; x.u = ((unsigned int)u) << 16;
  return x.f;
}
__device__ __forceinline__ void gload_lds16(const void* g, void* l) {
  __builtin_amdgcn_global_load_lds((const __attribute__((address_space(1))) void*)g,
                                   (__attribute__((address_space(3))) void*)l, 16, 0, 0);
}

// ---------------- cast x (f32 -> bf16), 4 elems/thread ----------------
__global__ void cast_f32_bf16(const float* __restrict__ src, unsigned short* __restrict__ dst) {
  int i = blockIdx.x * blockDim.x + threadIdx.x;
  float4 v = reinterpret_cast<const float4*>(src)[i];
  ushort4 o;
  o.x = f2bf(v.x); o.y = f2bf(v.y); o.z = f2bf(v.z); o.w = f2bf(v.w);
  reinterpret_cast<ushort4*>(dst)[i] = o;
}

// ------------- transpose+cast: src (R x C) f32 -> dst (C x R) bf16 -------------
__global__ void transpose_cast(const float* __restrict__ src, unsigned short* __restrict__ dst,
                               int R, int C) {
  __shared__ float tile[32][33];
  int c0 = blockIdx.x * 32, r0 = blockIdx.y * 32;
  int tx = threadIdx.x, ty = threadIdx.y;  // 32 x 8
#pragma unroll
  for (int i = 0; i < 4; ++i)
    tile[ty + i * 8][tx] = src[(size_t)(r0 + ty + i * 8) * C + (c0 + tx)];
  __syncthreads();
#pragma unroll
  for (int i = 0; i < 4; ++i)
    dst[(size_t)(c0 + ty + i * 8) * R + (r0 + tx)] = f2bf(tile[tx][ty + i * 8]);
}

// ====== 256x256 GEMM, ring-7 pipeline + 1 barrier/phase + reg-frag prefetch ======
// 512 threads = 8 waves (2M x 4N). BK=64. LDS = 8 slots x 16 KB = 128 KiB dynamic.
// Half-tile stream j = 4t+ht, ht: 0=A.h0 1=B.h0 2=B.h1 3=A.h1. Half j -> slot j%7,
// staged at phase j-5. Slot 7 = tail-dummy scratch. Per-phase vmcnt(6): half staged
// at phase f is landed by the vmcnt of phase f+3 (3 halves / 6 loads in flight).
// Phase = [stage; vmcnt(6); s_barrier; prefetch-ds_reads (next phase's frags);
//          setprio(1); 16 MFMA (current frags); setprio(0)].
// Prefetch chain (reads exactly at first-availability):
//   p0: MFMA(aA,b0) + read b1   (staged 4t-3, avail 4t)
//   p1: MFMA(aA,b1) + read aB   (staged 4t-2, avail 4t+1)
//   p2: MFMA(aB,b0) + read aA'  (staged 4t-1, avail 4t+2)
//   p3: MFMA(aB,b1) + read b0'  (staged 4t,   avail 4t+3)
// Reg liveness: each buffer overwritten >=1 phase after its last MFMA use (anti-dep
// enforced by regalloc). ds_reads now overlap the MFMA window within each wave; their
// lgkmcnt wait lands a full phase later.
// Swizzle (T2): row r (128B) holds 16B-chunk s at byte (s^(r&7))*16.
// EPI 0: bf16 split into Q/K/V (B,T,D). EPI 1: f32 + bias.
template <int EPI>
__global__ __launch_bounds__(512, 2)
void gemm256(const unsigned short* __restrict__ A, const unsigned short* __restrict__ Bt,
             unsigned short* __restrict__ Qo, unsigned short* __restrict__ Ko,
             unsigned short* __restrict__ Vo, float* __restrict__ Cf,
             const float* __restrict__ bias, int M, int N, int K) {
  extern __shared__ __align__(16) char lds[];
  const int tid = threadIdx.x;
  const int lane = tid & 63, wid = tid >> 6;
  const int wm = wid >> 2, wn = wid & 3;
  const int fr = lane & 15, fq = lane >> 4;

  // XCD swizzle (gridDim.x % 8 == 0 for both shapes)
  const int nbn = N >> 8;
  const int cpx = gridDim.x >> 3;
  const int id = blockIdx.x;
  const int sw = (id & 7) * cpx + (id >> 3);
  const int bm = sw / nbn, bn = sw % nbn;
  const int row0 = bm << 8, col0 = bn << 8;

  const int NT = K >> 6;

  // staging: thread covers row srow (+64 for 2nd issue), 16B at XOR-pre-swizzled col
  const int srow = tid >> 3;
  const int scol = ((tid & 7) ^ (srow & 7)) << 3;  // elems

  auto stage = [&](int j, int slot) {
    if (j < 4 * NT) {
      const int t = j >> 2, ht = j & 3;
      const int isB = (ht == 1 || ht == 2);
      const int h = (ht >= 2) ? 1 : 0;
      const unsigned short* base = isB ? Bt : A;
      const int grow = (isB ? col0 : row0) + h * 128 + srow;
      const unsigned short* src = base + (size_t)grow * K + t * 64 + scol;
      char* l0 = lds + slot * 16384 + tid * 16;
      gload_lds16(src, l0);
      gload_lds16(src + (size_t)64 * K, l0 + 8192);
    } else {
      // tail dummy: keep vmcnt stream uniform; lands in scratch slot 7
      char* l0 = lds + 7 * 16384 + tid * 16;
      gload_lds16(A + (tid << 3), l0);
      gload_lds16(A + (tid << 3), l0 + 8192);
    }
  };

  auto readA = [&](const char* base, bf16x8 (&dst)[4][2]) {
#pragma unroll
    for (int i2 = 0; i2 < 4; ++i2)
#pragma unroll
      for (int ks = 0; ks < 2; ++ks) {
        const int byte = ((((wm * 4 + i2) * 16 + fr) * 128) + ks * 64 + fq * 16) ^ ((fr & 7) << 4);
        dst[i2][ks] = *reinterpret_cast<const bf16x8*>(base + byte);
      }
  };
  auto readB = [&](const char* base, bf16x8 (&dst)[2][2]) {
#pragma unroll
    for (int j2 = 0; j2 < 2; ++j2)
#pragma unroll
      for (int ks = 0; ks < 2; ++ks) {
        const int byte = ((((wn * 2 + j2) * 16 + fr) * 128) + ks * 64 + fq * 16) ^ ((fr & 7) << 4);
        dst[j2][ks] = *reinterpret_cast<const bf16x8*>(base + byte);
      }
  };

  f32x4 acc[2][4][2][2] = {};
  bf16x8 aA[4][2], aB[4][2], b0[2][2], b1[2][2];

  // prologue: halves j=0..4 -> slots 0..4; vmcnt(6) forces j=0,1 landed
  stage(0, 0); stage(1, 1); stage(2, 2); stage(3, 3); stage(4, 4);
  asm volatile("s_waitcnt vmcnt(6)" ::: "memory");
  asm volatile("s_barrier" ::: "memory");
  readA(lds + 0 * 16384, aA);  // tile0 A.h0
  readB(lds + 1 * 16384, b0);  // tile0 B.h0

  int sA0 = 0, sB0 = 1, sB1 = 2, sA1 = 3, sst = 5;

  for (int k = 0; k < NT; ++k) {
    const int j0 = 4 * k + 5;

    // ---- phase 0: MFMA(aA,b0) || prefetch b1 ----
    {
      stage(j0 + 0, sst); sst = (sst == 6) ? 0 : sst + 1;
      asm volatile("s_waitcnt vmcnt(6)" ::: "memory");
      asm volatile("s_barrier" ::: "memory");
      readB(lds + sB1 * 16384, b1);
      __builtin_amdgcn_s_setprio(1);
#pragma unroll
      for (int i2 = 0; i2 < 4; ++i2)
#pragma unroll
        for (int j2 = 0; j2 < 2; ++j2)
#pragma unroll
          for (int ks = 0; ks < 2; ++ks)
            acc[0][i2][0][j2] =
                __builtin_amdgcn_mfma_f32_16x16x32_bf16(aA[i2][ks], b0[j2][ks], acc[0][i2][0][j2], 0, 0, 0);
      __builtin_amdgcn_s_setprio(0);
    }

    // ---- phase 1: MFMA(aA,b1) || prefetch aB ----
    {
      stage(j0 + 1, sst); sst = (sst == 6) ? 0 : sst + 1;
      asm volatile("s_waitcnt vmcnt(6)" ::: "memory");
      asm volatile("s_barrier" ::: "memory");
      readA(lds + sA1 * 16384, aB);
      __builtin_amdgcn_s_setprio(1);
#pragma unroll
      for (int i2 = 0; i2 < 4; ++i2)
#pragma unroll
        for (int j2 = 0; j2 < 2; ++j2)
#pragma unroll
          for (int ks = 0; ks < 2; ++ks)
            acc[0][i2][1][j2] =
                __builtin_amdgcn_mfma_f32_16x16x32_bf16(aA[i2][ks], b1[j2][ks], acc[0][i2][1][j2], 0, 0, 0);
      __builtin_amdgcn_s_setprio(0);
    }

    // ---- phase 2: MFMA(aB,b0) || prefetch aA of tile k+1 ----
    {
      stage(j0 + 2, sst); sst = (sst == 6) ? 0 : sst + 1;
      asm volatile("s_waitcnt vmcnt(6)" ::: "memory");
      asm volatile("s_barrier" ::: "memory");
      int s = sA0 + 4; if (s >= 7) s -= 7;
      readA(lds + s * 16384, aA);
      __builtin_amdgcn_s_setprio(1);
#pragma unroll
      for (int i2 = 0; i2 < 4; ++i2)
#pragma unroll
        for (int j2 = 0; j2 < 2; ++j2)
#pragma unroll
          for (int ks = 0; ks < 2; ++ks)
            acc[1][i2][0][j2] =
                __builtin_amdgcn_mfma_f32_16x16x32_bf16(aB[i2][ks], b0[j2][ks], acc[1][i2][0][j2], 0, 0, 0);
      __builtin_amdgcn_s_setprio(0);
    }

    // ---- phase 3: MFMA(aB,b1) || prefetch b0 of tile k+1 ----
    {
      stage(j0 + 3, sst); sst = (sst == 6) ? 0 : sst + 1;
      asm volatile("s_waitcnt vmcnt(6)" ::: "memory");
      asm volatile("s_barrier" ::: "memory");
      int s = sB0 + 4; if (s >= 7) s -= 7;
      readB(lds + s * 16384, b0);
      __builtin_amdgcn_s_setprio(1);
#pragma unroll
      for (int i2 = 0; i2 < 4; ++i2)
#pragma unroll
        for (int j2 = 0; j2 < 2; ++j2)
#pragma unroll
          for (int ks = 0; ks < 2; ++ks)
            acc[1][i2][1][j2] =
                __builtin_amdgcn_mfma_f32_16x16x32_bf16(aB[i2][ks], b1[j2][ks], acc[1][i2][1][j2], 0, 0, 0);
      __builtin_amdgcn_s_setprio(0);
    }

    sA0 += 4; if (sA0 >= 7) sA0 -= 7;
    sB0 += 4; if (sB0 >= 7) sB0 -= 7;
    sB1 += 4; if (sB1 >= 7) sB1 -= 7;
    sA1 += 4; if (sA1 >= 7) sA1 -= 7;
  }

  asm volatile("s_waitcnt vmcnt(0)" ::: "memory");  // drain tail dummies

  // epilogue: C/D layout col = lane&15, row = (lane>>4)*4 + r
#pragma unroll
  for (int mh = 0; mh < 2; ++mh)
#pragma unroll
    for (int i2 = 0; i2 < 4; ++i2) {
      const int rbase = row0 + (mh * 8 + wm * 4 + i2) * 16 + fq * 4;
#pragma unroll
      for (int nh = 0; nh < 2; ++nh)
#pragma unroll
        for (int j2 = 0; j2 < 2; ++j2) {
          const int col = col0 + (nh * 8 + wn * 2 + j2) * 16 + fr;
#pragma unroll
          for (int r = 0; r < 4; ++r) {
            const float v = acc[mh][i2][nh][j2][r];
            const int row = rbase + r;
            if (EPI == 0) {
              const int seg = col >> 11, cc = col & 2047;
              unsigned short* dst = (seg == 0) ? Qo : (seg == 1 ? Ko : Vo);
              dst[(size_t)row * 2048 + cc] = f2bf(v);
            } else {
              Cf[(size_t)row * N + col] = v + bias[col];
            }
          }
        }
    }
}

// --------- attention diag + V scale, one head strip (64 t-rows) per block ---------
__global__ __launch_bounds__(256, 2)
void attn_diag_ov(const unsigned short* __restrict__ Q, const unsigned short* __restrict__ K,
                  const unsigned short* __restrict__ V, unsigned short* __restrict__ OV) {
  __shared__ __align__(16) unsigned short qs[64 * 128];
  __shared__ __align__(16) unsigned short ks[128 * 128];
  __shared__ float dlds[64];
  const int tid = threadIdx.x;
  const int lane = tid & 63, wid = tid >> 6;
  const int head = blockIdx.y;            // b*16 + n
  const int b = head >> 4, n = head & 15;
  const int t0 = blockIdx.x << 6;
  const size_t hoff = (size_t)head << 18;
  const unsigned short* Qh = Q + hoff;
  const unsigned short* Kh = K + hoff;
  const unsigned short* Vh = V + hoff;

  const char* qsrc = (const char*)(Qh + ((size_t)t0 << 7));
#pragma unroll
  for (int i = 0; i < 4; ++i) {
    const int fb = (i * 256 + tid) << 4;
    const int sb = fb ^ (((fb >> 8) & 7) << 4);
    gload_lds16(qsrc + sb, (char*)qs + fb);
  }

  const int fr = lane & 15;
  const int fkb = (lane >> 4) << 4;
  const int g4 = (lane >> 4) << 2;

  float rsum[4] = {0.f, 0.f, 0.f, 0.f};
  float dnum[4] = {0.f, 0.f, 0.f, 0.f};
  const float scale = 0.02209708691207961f;  // 1/sqrt(2048)
  bf16x8 afrag[4];

  for (int jc = 0; jc < 2048; jc += 128) {
    const char* ksrc = (const char*)(Kh + ((size_t)jc << 7));
#pragma unroll
    for (int i = 0; i < 8; ++i) {
      const int fb = (i * 256 + tid) << 4;
      const int sb = fb ^ (((fb >> 8) & 7) << 4);
      gload_lds16(ksrc + sb, (char*)ks + fb);
    }
    __syncthreads();
    if (jc == 0) {
#pragma unroll
      for (int kk = 0; kk < 4; ++kk) {
        const int row = wid * 16 + fr;
        const int byte = (row << 8) + (kk << 6) + fkb;
        afrag[kk] = *reinterpret_cast<const bf16x8*>((const char*)qs + (byte ^ ((row & 7) << 4)));
      }
    }
#pragma unroll
    for (int jt = 0; jt < 8; ++jt) {
      f32x4 acc = {0.f, 0.f, 0.f, 0.f};
#pragma unroll
      for (int kk = 0; kk < 4; ++kk) {
        const int row = jt * 16 + fr;
        const int byte = (row << 8) + (kk << 6) + fkb;
        bf16x8 bfrag = *reinterpret_cast<const bf16x8*>((const char*)ks + (byte ^ ((row & 7) << 4)));
        acc = __builtin_amdgcn_mfma_f32_16x16x32_bf16(afrag[kk], bfrag, acc, 0, 0, 0);
      }
      const int colj = jc + jt * 16 + fr;
      const int rowt = t0 + wid * 16 + g4;
#pragma unroll
      for (int r = 0; r < 4; ++r) {
        const float e = __expf(acc[r] * scale);
        rsum[r] += e;
        if (colj == rowt + r) dnum[r] = e;
      }
    }
    __syncthreads();
  }

#pragma unroll
  for (int r = 0; r < 4; ++r) {
#pragma unroll
    for (int s = 1; s < 16; s <<= 1) {
      rsum[r] += __shfl_xor(rsum[r], s, 64);
      dnum[r] += __shfl_xor(dnum[r], s, 64);
    }
  }
  if (fr == 0) {
#pragma unroll
    for (int r = 0; r < 4; ++r)
      dlds[wid * 16 + g4 + r] = dnum[r] / rsum[r];
  }
  __syncthreads();

  const unsigned short* vsrc = Vh + ((size_t)t0 << 7);
  unsigned short* dst = OV + ((size_t)((b << 11) + t0)) * 2048 + (n << 7);
#pragma unroll
  for (int c = 0; c < 4; ++c) {
    const int flat = (c * 256 + tid) << 3;
    const int row = flat >> 7, col = flat & 127;
    bf16x8 v = *reinterpret_cast<const bf16x8*>(vsrc + flat);
    const float d = dlds[row];
    bf16x8 o;
#pragma unroll
    for (int e = 0; e < 8; ++e)
      o[e] = (short)f2bf(bf2f((unsigned short)v[e]) * d);
    *reinterpret_cast<bf16x8*>(dst + (size_t)row * 2048 + col) = o;
  }
}

extern "C" void kernel_launch(void* const* d_in, const int* in_sizes, int n_in,
                              void* d_out, int out_size, void* d_ws, size_t ws_size,
                              hipStream_t stream) {
  const float* x = (const float*)d_in[0];        // (4,2048,2048)
  const float* w_qkv = (const float*)d_in[1];    // (2048,6144)
  const float* w_proj = (const float*)d_in[2];   // (2048,2048)
  const float* b_proj = (const float*)d_in[3];   // (2048,)
  float* out = (float*)d_out;                    // (4,2048,2048) f32

  char* p = (char*)d_ws;
  unsigned short* Xb = (unsigned short*)p;     p += (size_t)8192 * 2048 * 2;
  unsigned short* WqkvT = (unsigned short*)p;  p += (size_t)6144 * 2048 * 2;
  unsigned short* WprojT = (unsigned short*)p; p += (size_t)2048 * 2048 * 2;
  unsigned short* Qb = (unsigned short*)p;     p += (size_t)8192 * 2048 * 2;
  unsigned short* Kb = (unsigned short*)p;     p += (size_t)8192 * 2048 * 2;
  unsigned short* Vb = (unsigned short*)p;     p += (size_t)8192 * 2048 * 2;
  unsigned short* OV = (unsigned short*)p;     p += (size_t)8192 * 2048 * 2;

  // allow 128 KiB dynamic LDS (persistent function attribute; safe to repeat)
  (void)hipFuncSetAttribute((const void*)gemm256<0>,
                            hipFuncAttributeMaxDynamicSharedMemorySize, 131072);
  (void)hipFuncSetAttribute((const void*)gemm256<1>,
                            hipFuncAttributeMaxDynamicSharedMemorySize, 131072);

  cast_f32_bf16<<<16384, 256, 0, stream>>>(x, Xb);
  transpose_cast<<<dim3(192, 64), dim3(32, 8), 0, stream>>>(w_qkv, WqkvT, 2048, 6144);
  transpose_cast<<<dim3(64, 64), dim3(32, 8), 0, stream>>>(w_proj, WprojT, 2048, 2048);

  // QKV = Xb (8192x2048) * WqkvT^T -> split bf16 Q/K/V (B,T,D)
  gemm256<0><<<dim3(32 * 24), 512, 131072, stream>>>(Xb, WqkvT, Qb, Kb, Vb, nullptr, nullptr,
                                                     8192, 6144, 2048);
  // diag softmax + V scale -> OV (8192x2048) bf16
  attn_diag_ov<<<dim3(32, 64), 256, 0, stream>>>(Qb, Kb, Vb, OV);
  // out = OV * WprojT^T + b_proj (f32)
  gemm256<1><<<dim3(32 * 8), 512, 131072, stream>>>(OV, WprojT, nullptr, nullptr, nullptr, out,
                                                    b_proj, 8192, 2048, 2048);
}

// Round 7
// 375.682 us; speedup vs baseline: 1.5164x; 1.5164x over previous
//
#include <hip/hip_runtime.h>
#include <hip/hip_bf16.h>

typedef short bf16x8 __attribute__((ext_vector_type(8)));
typedef float f32x4 __attribute__((ext_vector_type(4)));

__device__ __forceinline__ unsigned short f2bf(float f) {
  union { float f; unsigned int u; } x; x.f = f;
  return (unsigned short)((x.u + 0x7fffu + ((x.u >> 16) & 1u)) >> 16);
}
__device__ __forceinline__ float bf2f(unsigned short u) {
  union { unsigned int u; float f; } x; x.u = ((unsigned int)u) << 16;
  return x.f;
}
__device__ __forceinline__ void gload_lds16(const void* g, void* l) {
  __builtin_amdgcn_global_load_lds((const __attribute__((address_space(1))) void*)g,
                                   (__attribute__((address_space(3))) void*)l, 16, 0, 0);
}

// ---------------- cast x (f32 -> bf16), 4 elems/thread ----------------
__global__ void cast_f32_bf16(const float* __restrict__ src, unsigned short* __restrict__ dst) {
  int i = blockIdx.x * blockDim.x + threadIdx.x;
  float4 v = reinterpret_cast<const float4*>(src)[i];
  ushort4 o;
  o.x = f2bf(v.x); o.y = f2bf(v.y); o.z = f2bf(v.z); o.w = f2bf(v.w);
  reinterpret_cast<ushort4*>(dst)[i] = o;
}

// ------------- transpose+cast: src (R x C) f32 -> dst (C x R) bf16 -------------
__global__ void transpose_cast(const float* __restrict__ src, unsigned short* __restrict__ dst,
                               int R, int C) {
  __shared__ float tile[32][33];
  int c0 = blockIdx.x * 32, r0 = blockIdx.y * 32;
  int tx = threadIdx.x, ty = threadIdx.y;  // 32 x 8
#pragma unroll
  for (int i = 0; i < 4; ++i)
    tile[ty + i * 8][tx] = src[(size_t)(r0 + ty + i * 8) * C + (c0 + tx)];
  __syncthreads();
#pragma unroll
  for (int i = 0; i < 4; ++i)
    dst[(size_t)(c0 + ty + i * 8) * R + (r0 + tx)] = f2bf(tile[tx][ty + i * 8]);
}

// ============ 256x256 GEMM, half-tile RING-7 pipeline, 1 barrier/phase (R5) ============
// 512 threads = 8 waves (2M x 4N). BK=64. LDS = 8 slots x 16 KB = 128 KiB dynamic.
// Half-tile stream j = 4t+ht, ht: 0=A.h0 1=B.h0 2=B.h1 3=A.h1 (first-reader order).
// Half j -> slot j%7, staged at global phase j-5. Slot 7 = tail-dummy scratch.
// Phase structure: [ds_reads; stage(j); vmcnt(6); s_barrier; setprio(1); MFMA; setprio(0)].
// Swizzle (T2): row r (128B) holds 16B-chunk s at byte (s^(r&7))*16.
// EPI 0: bf16 split into Q/K/V (B,T,D). EPI 1: f32 + bias.
template <int EPI>
__global__ __launch_bounds__(512, 2)
void gemm256(const unsigned short* __restrict__ A, const unsigned short* __restrict__ Bt,
             unsigned short* __restrict__ Qo, unsigned short* __restrict__ Ko,
             unsigned short* __restrict__ Vo, float* __restrict__ Cf,
             const float* __restrict__ bias, int M, int N, int K) {
  extern __shared__ __align__(16) char lds[];
  const int tid = threadIdx.x;
  const int lane = tid & 63, wid = tid >> 6;
  const int wm = wid >> 2, wn = wid & 3;
  const int fr = lane & 15, fq = lane >> 4;

  // XCD swizzle (gridDim.x % 8 == 0 for both shapes)
  const int nbn = N >> 8;
  const int cpx = gridDim.x >> 3;
  const int id = blockIdx.x;
  const int sw = (id & 7) * cpx + (id >> 3);
  const int bm = sw / nbn, bn = sw % nbn;
  const int row0 = bm << 8, col0 = bn << 8;

  const int NT = K >> 6;

  // staging: thread covers row srow (+64 for 2nd issue), 16B at XOR-pre-swizzled col
  const int srow = tid >> 3;
  const int scol = ((tid & 7) ^ (srow & 7)) << 3;  // elems

  auto stage = [&](int j, int slot) {
    if (j < 4 * NT) {
      const int t = j >> 2, ht = j & 3;
      const int isB = (ht == 1 || ht == 2);
      const int h = (ht >= 2) ? 1 : 0;
      const unsigned short* base = isB ? Bt : A;
      const int grow = (isB ? col0 : row0) + h * 128 + srow;
      const unsigned short* src = base + (size_t)grow * K + t * 64 + scol;
      char* l0 = lds + slot * 16384 + tid * 16;
      gload_lds16(src, l0);
      gload_lds16(src + (size_t)64 * K, l0 + 8192);
    } else {
      // tail dummy: keep vmcnt stream uniform; lands in scratch slot 7
      char* l0 = lds + 7 * 16384 + tid * 16;
      gload_lds16(A + (tid << 3), l0);
      gload_lds16(A + (tid << 3), l0 + 8192);
    }
  };

  f32x4 acc[2][4][2][2] = {};

  // prologue: halves j=0..4 -> slots 0..4; vmcnt(6) forces j=0,1 landed (phase-0 reads)
  stage(0, 0); stage(1, 1); stage(2, 2); stage(3, 3); stage(4, 4);
  asm volatile("s_waitcnt vmcnt(6)" ::: "memory");
  asm volatile("s_barrier" ::: "memory");

  int sA0 = 0, sB0 = 1, sB1 = 2, sA1 = 3, sst = 5;

  for (int k = 0; k < NT; ++k) {
    const int j0 = 4 * k + 5;
    bf16x8 a[4][2], b0[2][2], b1[2][2];

    // ---- phase 0: (mh=0, nh=0) — LDS-read a(h0), b0(h0) ----
    {
      const char* Ab = lds + sA0 * 16384;
      const char* Bb = lds + sB0 * 16384;
#pragma unroll
      for (int i2 = 0; i2 < 4; ++i2)
#pragma unroll
        for (int ks = 0; ks < 2; ++ks) {
          const int byte = ((((wm * 4 + i2) * 16 + fr) * 128) + ks * 64 + fq * 16) ^ ((fr & 7) << 4);
          a[i2][ks] = *reinterpret_cast<const bf16x8*>(Ab + byte);
        }
#pragma unroll
      for (int j2 = 0; j2 < 2; ++j2)
#pragma unroll
        for (int ks = 0; ks < 2; ++ks) {
          const int byte = ((((wn * 2 + j2) * 16 + fr) * 128) + ks * 64 + fq * 16) ^ ((fr & 7) << 4);
          b0[j2][ks] = *reinterpret_cast<const bf16x8*>(Bb + byte);
        }
      stage(j0 + 0, sst); sst = (sst == 6) ? 0 : sst + 1;
      asm volatile("s_waitcnt vmcnt(6)" ::: "memory");
      asm volatile("s_barrier" ::: "memory");
      __builtin_amdgcn_s_setprio(1);
#pragma unroll
      for (int i2 = 0; i2 < 4; ++i2)
#pragma unroll
        for (int j2 = 0; j2 < 2; ++j2)
#pragma unroll
          for (int ks = 0; ks < 2; ++ks)
            acc[0][i2][0][j2] =
                __builtin_amdgcn_mfma_f32_16x16x32_bf16(a[i2][ks], b0[j2][ks], acc[0][i2][0][j2], 0, 0, 0);
      __builtin_amdgcn_s_setprio(0);
    }

    // ---- phase 1: (mh=0, nh=1) — LDS-read b1(h1); a cached ----
    {
      const char* Bb = lds + sB1 * 16384;
#pragma unroll
      for (int j2 = 0; j2 < 2; ++j2)
#pragma unroll
        for (int ks = 0; ks < 2; ++ks) {
          const int byte = ((((wn * 2 + j2) * 16 + fr) * 128) + ks * 64 + fq * 16) ^ ((fr & 7) << 4);
          b1[j2][ks] = *reinterpret_cast<const bf16x8*>(Bb + byte);
        }
      stage(j0 + 1, sst); sst = (sst == 6) ? 0 : sst + 1;
      asm volatile("s_waitcnt vmcnt(6)" ::: "memory");
      asm volatile("s_barrier" ::: "memory");
      __builtin_amdgcn_s_setprio(1);
#pragma unroll
      for (int i2 = 0; i2 < 4; ++i2)
#pragma unroll
        for (int j2 = 0; j2 < 2; ++j2)
#pragma unroll
          for (int ks = 0; ks < 2; ++ks)
            acc[0][i2][1][j2] =
                __builtin_amdgcn_mfma_f32_16x16x32_bf16(a[i2][ks], b1[j2][ks], acc[0][i2][1][j2], 0, 0, 0);
      __builtin_amdgcn_s_setprio(0);
    }

    // ---- phase 2: (mh=1, nh=0) — LDS-read a(h1); b0 cached ----
    {
      const char* Ab = lds + sA1 * 16384;
#pragma unroll
      for (int i2 = 0; i2 < 4; ++i2)
#pragma unroll
        for (int ks = 0; ks < 2; ++ks) {
          const int byte = ((((wm * 4 + i2) * 16 + fr) * 128) + ks * 64 + fq * 16) ^ ((fr & 7) << 4);
          a[i2][ks] = *reinterpret_cast<const bf16x8*>(Ab + byte);
        }
      stage(j0 + 2, sst); sst = (sst == 6) ? 0 : sst + 1;
      asm volatile("s_waitcnt vmcnt(6)" ::: "memory");
      asm volatile("s_barrier" ::: "memory");
      __builtin_amdgcn_s_setprio(1);
#pragma unroll
      for (int i2 = 0; i2 < 4; ++i2)
#pragma unroll
        for (int j2 = 0; j2 < 2; ++j2)
#pragma unroll
          for (int ks = 0; ks < 2; ++ks)
            acc[1][i2][0][j2] =
                __builtin_amdgcn_mfma_f32_16x16x32_bf16(a[i2][ks], b0[j2][ks], acc[1][i2][0][j2], 0, 0, 0);
      __builtin_amdgcn_s_setprio(0);
    }

    // ---- phase 3: (mh=1, nh=1) — a and b1 cached, no LDS reads ----
    {
      stage(j0 + 3, sst); sst = (sst == 6) ? 0 : sst + 1;
      asm volatile("s_waitcnt vmcnt(6)" ::: "memory");
      asm volatile("s_barrier" ::: "memory");
      __builtin_amdgcn_s_setprio(1);
#pragma unroll
      for (int i2 = 0; i2 < 4; ++i2)
#pragma unroll
        for (int j2 = 0; j2 < 2; ++j2)
#pragma unroll
          for (int ks = 0; ks < 2; ++ks)
            acc[1][i2][1][j2] =
                __builtin_amdgcn_mfma_f32_16x16x32_bf16(a[i2][ks], b1[j2][ks], acc[1][i2][1][j2], 0, 0, 0);
      __builtin_amdgcn_s_setprio(0);
    }

    sA0 += 4; if (sA0 >= 7) sA0 -= 7;
    sB0 += 4; if (sB0 >= 7) sB0 -= 7;
    sB1 += 4; if (sB1 >= 7) sB1 -= 7;
    sA1 += 4; if (sA1 >= 7) sA1 -= 7;
  }

  asm volatile("s_waitcnt vmcnt(0)" ::: "memory");  // drain tail dummies

  // epilogue: C/D layout col = lane&15, row = (lane>>4)*4 + r
#pragma unroll
  for (int mh = 0; mh < 2; ++mh)
#pragma unroll
    for (int i2 = 0; i2 < 4; ++i2) {
      const int rbase = row0 + (mh * 8 + wm * 4 + i2) * 16 + fq * 4;
#pragma unroll
      for (int nh = 0; nh < 2; ++nh)
#pragma unroll
        for (int j2 = 0; j2 < 2; ++j2) {
          const int col = col0 + (nh * 8 + wn * 2 + j2) * 16 + fr;
#pragma unroll
          for (int r = 0; r < 4; ++r) {
            const float v = acc[mh][i2][nh][j2][r];
            const int row = rbase + r;
            if (EPI == 0) {
              const int seg = col >> 11, cc = col & 2047;
              unsigned short* dst = (seg == 0) ? Qo : (seg == 1 ? Ko : Vo);
              dst[(size_t)row * 2048 + cc] = f2bf(v);
            } else {
              Cf[(size_t)row * N + col] = v + bias[col];
            }
          }
        }
    }
}

// ========== attention diag + V scale v2: 256 t-rows per block, 8 waves ==========
// Grid 512: dispatch d -> head = d%64, tb = d/64  (all 8 blocks of a head land on
// XCD head%8 -> K-head stays L2-resident; 8 heads x 512 KB = 4 MB per XCD).
// Per wave: 32 Q rows (2 x 16-row frag groups) held in registers, loaded directly
// from global (64B/row segments, read once). K double-buffered in LDS (2 x 32 KB),
// 1 barrier per 128-col K-tile. K rows are 256 B = 16 chunks of 16B; swizzle chunk
// s -> s^(row&15) (bijective; column reads hit <=2 lanes per 4-bank group).
__global__ __launch_bounds__(512, 2)
void attn_diag_ov(const unsigned short* __restrict__ Q, const unsigned short* __restrict__ K,
                  const unsigned short* __restrict__ V, unsigned short* __restrict__ OV) {
  __shared__ __align__(16) char ks[2][128 * 256];  // 2 x 32 KB
  __shared__ float dlds[256];
  const int tid = threadIdx.x;
  const int lane = tid & 63, wid = tid >> 6;
  const int d = blockIdx.x;
  const int head = d & 63, tb = d >> 6;
  const int b = head >> 4, n = head & 15;
  const int t0 = tb << 8;
  const size_t hoff = (size_t)head << 18;  // head * 2048*128
  const unsigned short* Qh = Q + hoff;
  const unsigned short* Kh = K + hoff;
  const unsigned short* Vh = V + hoff;

  const int fr = lane & 15, fq = lane >> 4;
  const int g4 = fq << 2;
  const int qrow0 = t0 + wid * 32;

  // Q fragments direct from global: A-frag rows = Q rows, 4 k-chunks of 8 elems
  bf16x8 qf[2][4];
#pragma unroll
  for (int m = 0; m < 2; ++m)
#pragma unroll
    for (int kk = 0; kk < 4; ++kk)
      qf[m][kk] = *reinterpret_cast<const bf16x8*>(
          Qh + (size_t)(qrow0 + m * 16 + fr) * 128 + kk * 32 + fq * 8);

  // stage K-tile (128 rows x 128 cols bf16 = 32 KB) into buffer s; pre-swizzled source
  auto stageK = [&](int jc, int s) {
    const char* ksrc = (const char*)(Kh + ((size_t)jc << 7));
#pragma unroll
    for (int i = 0; i < 4; ++i) {
      const int flat = i * 8192 + tid * 16;
      const int row = flat >> 8, c = (flat >> 4) & 15;
      const int sb = (row << 8) + ((c ^ (row & 15)) << 4);
      gload_lds16(ksrc + sb, &ks[s][0] + flat);
    }
  };

  float rsum[2][4] = {};
  float dnum[2][4] = {};
  const float scale = 0.02209708691207961f;  // 1/sqrt(2048)

  stageK(0, 0);
  asm volatile("s_waitcnt vmcnt(0)" ::: "memory");
  asm volatile("s_barrier" ::: "memory");

  for (int t = 0; t < 16; ++t) {
    const int jc = t << 7;
    if (t < 15) stageK(jc + 128, (t + 1) & 1);
    const char* buf = &ks[t & 1][0];
#pragma unroll
    for (int jt = 0; jt < 8; ++jt) {
      bf16x8 bfrag[4];
#pragma unroll
      for (int kk = 0; kk < 4; ++kk) {
        const int row = jt * 16 + fr;
        const int s = kk * 4 + fq;
        bfrag[kk] = *reinterpret_cast<const bf16x8*>(buf + (row << 8) + ((s ^ (row & 15)) << 4));
      }
#pragma unroll
      for (int m = 0; m < 2; ++m) {
        f32x4 acc = {0.f, 0.f, 0.f, 0.f};
#pragma unroll
        for (int kk = 0; kk < 4; ++kk)
          acc = __builtin_amdgcn_mfma_f32_16x16x32_bf16(qf[m][kk], bfrag[kk], acc, 0, 0, 0);
        const int colj = jc + jt * 16 + fr;
        const int rowt = qrow0 + m * 16 + g4;
#pragma unroll
        for (int r = 0; r < 4; ++r) {
          const float e = __expf(acc[r] * scale);
          rsum[m][r] += e;
          if (colj == rowt + r) dnum[m][r] = e;
        }
      }
    }
    asm volatile("s_waitcnt vmcnt(0)" ::: "memory");
    asm volatile("s_barrier" ::: "memory");
  }

  // reduce across the 16 fr-lanes (xor 1,2,4,8 keeps fq bits intact)
#pragma unroll
  for (int m = 0; m < 2; ++m)
#pragma unroll
    for (int r = 0; r < 4; ++r) {
#pragma unroll
      for (int s = 1; s < 16; s <<= 1) {
        rsum[m][r] += __shfl_xor(rsum[m][r], s, 64);
        dnum[m][r] += __shfl_xor(dnum[m][r], s, 64);
      }
      if (fr == 0) dlds[wid * 32 + m * 16 + g4 + r] = dnum[m][r] / rsum[m][r];
    }
  __syncthreads();

  // OV write: rows t0..t0+255, cols n*128..+128 of OV (8192 x 2048)
  const unsigned short* vsrc = Vh + ((size_t)t0 << 7);
  unsigned short* dst = OV + ((size_t)((b << 11) + t0)) * 2048 + (n << 7);
#pragma unroll
  for (int c = 0; c < 8; ++c) {
    const int flat = (c * 512 + tid) << 3;
    const int row = flat >> 7, col = flat & 127;
    bf16x8 v = *reinterpret_cast<const bf16x8*>(vsrc + flat);
    const float dd = dlds[row];
    bf16x8 o;
#pragma unroll
    for (int e = 0; e < 8; ++e)
      o[e] = (short)f2bf(bf2f((unsigned short)v[e]) * dd);
    *reinterpret_cast<bf16x8*>(dst + (size_t)row * 2048 + col) = o;
  }
}

extern "C" void kernel_launch(void* const* d_in, const int* in_sizes, int n_in,
                              void* d_out, int out_size, void* d_ws, size_t ws_size,
                              hipStream_t stream) {
  const float* x = (const float*)d_in[0];        // (4,2048,2048)
  const float* w_qkv = (const float*)d_in[1];    // (2048,6144)
  const float* w_proj = (const float*)d_in[2];   // (2048,2048)
  const float* b_proj = (const float*)d_in[3];   // (2048,)
  float* out = (float*)d_out;                    // (4,2048,2048) f32

  char* p = (char*)d_ws;
  unsigned short* Xb = (unsigned short*)p;     p += (size_t)8192 * 2048 * 2;
  unsigned short* WqkvT = (unsigned short*)p;  p += (size_t)6144 * 2048 * 2;
  unsigned short* WprojT = (unsigned short*)p; p += (size_t)2048 * 2048 * 2;
  unsigned short* Qb = (unsigned short*)p;     p += (size_t)8192 * 2048 * 2;
  unsigned short* Kb = (unsigned short*)p;     p += (size_t)8192 * 2048 * 2;
  unsigned short* Vb = (unsigned short*)p;     p += (size_t)8192 * 2048 * 2;
  unsigned short* OV = (unsigned short*)p;     p += (size_t)8192 * 2048 * 2;

  // allow 128 KiB dynamic LDS (persistent function attribute; safe to repeat)
  (void)hipFuncSetAttribute((const void*)gemm256<0>,
                            hipFuncAttributeMaxDynamicSharedMemorySize, 131072);
  (void)hipFuncSetAttribute((const void*)gemm256<1>,
                            hipFuncAttributeMaxDynamicSharedMemorySize, 131072);

  cast_f32_bf16<<<16384, 256, 0, stream>>>(x, Xb);
  transpose_cast<<<dim3(192, 64), dim3(32, 8), 0, stream>>>(w_qkv, WqkvT, 2048, 6144);
  transpose_cast<<<dim3(64, 64), dim3(32, 8), 0, stream>>>(w_proj, WprojT, 2048, 2048);

  // QKV = Xb (8192x2048) * WqkvT^T -> split bf16 Q/K/V (B,T,D)
  gemm256<0><<<dim3(32 * 24), 512, 131072, stream>>>(Xb, WqkvT, Qb, Kb, Vb, nullptr, nullptr,
                                                     8192, 6144, 2048);
  // diag softmax + V scale -> OV (8192x2048) bf16
  attn_diag_ov<<<dim3(512), 512, 0, stream>>>(Qb, Kb, Vb, OV);
  // out = OV * WprojT^T + b_proj (f32)
  gemm256<1><<<dim3(32 * 8), 512, 131072, stream>>>(OV, WprojT, nullptr, nullptr, nullptr, out,
                                                    b_proj, 8192, 2048, 2048);
}

// Round 8
// 352.959 us; speedup vs baseline: 1.6141x; 1.0644x over previous
//
#include <hip/hip_runtime.h>
#include <hip/hip_bf16.h>

typedef short bf16x8 __attribute__((ext_vector_type(8)));
typedef float f32x4 __attribute__((ext_vector_type(4)));

__device__ __forceinline__ unsigned short f2bf(float f) {
  union { float f; unsigned int u; } x; x.f = f;
  return (unsigned short)((x.u + 0x7fffu + ((x.u >> 16) & 1u)) >> 16);
}
__device__ __forceinline__ float bf2f(unsigned short u) {
  union { unsigned int u; float f; } x; x.u = ((unsigned int)u) << 16;
  return x.f;
}
__device__ __forceinline__ void gload_lds16(const void* g, void* l) {
  __builtin_amdgcn_global_load_lds((const __attribute__((address_space(1))) void*)g,
                                   (__attribute__((address_space(3))) void*)l, 16, 0, 0);
}

// ---------------- cast x (f32 -> bf16), 4 elems/thread ----------------
__global__ void cast_f32_bf16(const float* __restrict__ src, unsigned short* __restrict__ dst) {
  int i = blockIdx.x * blockDim.x + threadIdx.x;
  float4 v = reinterpret_cast<const float4*>(src)[i];
  ushort4 o;
  o.x = f2bf(v.x); o.y = f2bf(v.y); o.z = f2bf(v.z); o.w = f2bf(v.w);
  reinterpret_cast<ushort4*>(dst)[i] = o;
}

// ------------- transpose+cast: src (R x C) f32 -> dst (C x R) bf16 -------------
__global__ void transpose_cast(const float* __restrict__ src, unsigned short* __restrict__ dst,
                               int R, int C) {
  __shared__ float tile[32][33];
  int c0 = blockIdx.x * 32, r0 = blockIdx.y * 32;
  int tx = threadIdx.x, ty = threadIdx.y;  // 32 x 8
#pragma unroll
  for (int i = 0; i < 4; ++i)
    tile[ty + i * 8][tx] = src[(size_t)(r0 + ty + i * 8) * C + (c0 + tx)];
  __syncthreads();
#pragma unroll
  for (int i = 0; i < 4; ++i)
    dst[(size_t)(c0 + ty + i * 8) * R + (r0 + tx)] = f2bf(tile[tx][ty + i * 8]);
}

// ====== 256x256 GEMM, ring-8 half-tile pipeline, barrier every 2 phases ======
// 512 threads = 8 waves (2M x 4N). BK=64. LDS = 8 slots x 16 KB = 128 KiB dynamic.
// Half-tile stream j = 4t+ht, ht: 0=A.h0 1=B.h0 2=B.h1 3=A.h1. Half j -> slot j&7,
// staged at phase j-6 (prologue j=0..5; in-loop phase f stages j=f+6; j>=4NT =
// dummy loads continuing the stream into slot j&7).
// Per-phase vmcnt(6) (3 stage-pairs in flight) => half j own-drained at vmcnt@(j-3).
// Barriers ONLY inside odd phases (p1,p3), between vmcnt and MFMA.
// Race ledger: first-read of j at r(j) in {j-1, j}; RAW needs odd phase in
// [j-3, r(j)-1] superset [j-3, j-2] -> always holds. WAR: overwriter j+8 staged at
// phase j+2 after a barrier in [r(j), j+1] -> always holds. Waves drift across
// 2-phase windows => one wave's MFMA overlaps siblings' ds_reads.
// Fragment reuse: a cached p0->p1 / p2->p3; b0 cached p0->p2; b1 cached p1->p3.
// Swizzle (T2): row r (128B) holds 16B-chunk s at byte (s^(r&7))*16.
// EPI 0: bf16 split into Q/K/V (B,T,D). EPI 1: f32 + bias.
template <int EPI>
__global__ __launch_bounds__(512, 2)
void gemm256(const unsigned short* __restrict__ A, const unsigned short* __restrict__ Bt,
             unsigned short* __restrict__ Qo, unsigned short* __restrict__ Ko,
             unsigned short* __restrict__ Vo, float* __restrict__ Cf,
             const float* __restrict__ bias, int M, int N, int K) {
  extern __shared__ __align__(16) char lds[];
  const int tid = threadIdx.x;
  const int lane = tid & 63, wid = tid >> 6;
  const int wm = wid >> 2, wn = wid & 3;
  const int fr = lane & 15, fq = lane >> 4;

  // XCD swizzle (gridDim.x % 8 == 0 for both shapes)
  const int nbn = N >> 8;
  const int cpx = gridDim.x >> 3;
  const int id = blockIdx.x;
  const int sw = (id & 7) * cpx + (id >> 3);
  const int bm = sw / nbn, bn = sw % nbn;
  const int row0 = bm << 8, col0 = bn << 8;

  const int NT = K >> 6;

  // staging: thread covers row srow (+64 for 2nd issue), 16B at XOR-pre-swizzled col
  const int srow = tid >> 3;
  const int scol = ((tid & 7) ^ (srow & 7)) << 3;  // elems

  auto stage = [&](int j) {
    char* l0 = lds + (j & 7) * 16384 + tid * 16;
    if (j < 4 * NT) {
      const int t = j >> 2, ht = j & 3;
      const int isB = (ht == 1 || ht == 2);
      const int h = (ht >= 2) ? 1 : 0;
      const unsigned short* base = isB ? Bt : A;
      const int grow = (isB ? col0 : row0) + h * 128 + srow;
      const unsigned short* src = base + (size_t)grow * K + t * 64 + scol;
      gload_lds16(src, l0);
      gload_lds16(src + (size_t)64 * K, l0 + 8192);
    } else {
      // tail dummy: keeps the vmcnt stream uniform; target slot's half is dead
      gload_lds16(A + (tid << 3), l0);
      gload_lds16(A + (tid << 3), l0 + 8192);
    }
  };

  f32x4 acc[2][4][2][2] = {};

  // prologue: halves j=0..5 -> slots 0..5; vmcnt(6) drains j=0,1,2; publish
  stage(0); stage(1); stage(2); stage(3); stage(4); stage(5);
  asm volatile("s_waitcnt vmcnt(6)" ::: "memory");
  asm volatile("s_barrier" ::: "memory");

  for (int k = 0; k < NT; ++k) {
    const int j0 = 4 * k + 6;           // stage stream position at p0
    const int sb = (k & 1) << 2;        // this tile's slot base (0 or 4)
    const char* As0 = lds + (sb + 0) * 16384;
    const char* Bs0 = lds + (sb + 1) * 16384;
    const char* Bs1 = lds + (sb + 2) * 16384;
    const char* As1 = lds + (sb + 3) * 16384;
    bf16x8 a[4][2], b0[2][2], b1[2][2];

    // ---- phase 0 (even, no barrier): read a(h0), b0(h0); MFMA acc[0][*][0] ----
    {
#pragma unroll
      for (int i2 = 0; i2 < 4; ++i2)
#pragma unroll
        for (int ks = 0; ks < 2; ++ks) {
          const int byte = ((((wm * 4 + i2) * 16 + fr) * 128) + ks * 64 + fq * 16) ^ ((fr & 7) << 4);
          a[i2][ks] = *reinterpret_cast<const bf16x8*>(As0 + byte);
        }
#pragma unroll
      for (int j2 = 0; j2 < 2; ++j2)
#pragma unroll
        for (int ks = 0; ks < 2; ++ks) {
          const int byte = ((((wn * 2 + j2) * 16 + fr) * 128) + ks * 64 + fq * 16) ^ ((fr & 7) << 4);
          b0[j2][ks] = *reinterpret_cast<const bf16x8*>(Bs0 + byte);
        }
      stage(j0 + 0);
      asm volatile("s_waitcnt vmcnt(6)" ::: "memory");
      __builtin_amdgcn_s_setprio(1);
#pragma unroll
      for (int i2 = 0; i2 < 4; ++i2)
#pragma unroll
        for (int j2 = 0; j2 < 2; ++j2)
#pragma unroll
          for (int ks = 0; ks < 2; ++ks)
            acc[0][i2][0][j2] =
                __builtin_amdgcn_mfma_f32_16x16x32_bf16(a[i2][ks], b0[j2][ks], acc[0][i2][0][j2], 0, 0, 0);
      __builtin_amdgcn_s_setprio(0);
    }

    // ---- phase 1 (odd, barrier): read b1(h1); MFMA acc[0][*][1] ----
    {
#pragma unroll
      for (int j2 = 0; j2 < 2; ++j2)
#pragma unroll
        for (int ks = 0; ks < 2; ++ks) {
          const int byte = ((((wn * 2 + j2) * 16 + fr) * 128) + ks * 64 + fq * 16) ^ ((fr & 7) << 4);
          b1[j2][ks] = *reinterpret_cast<const bf16x8*>(Bs1 + byte);
        }
      stage(j0 + 1);
      asm volatile("s_waitcnt vmcnt(6)" ::: "memory");
      asm volatile("s_barrier" ::: "memory");
      __builtin_amdgcn_s_setprio(1);
#pragma unroll
      for (int i2 = 0; i2 < 4; ++i2)
#pragma unroll
        for (int j2 = 0; j2 < 2; ++j2)
#pragma unroll
          for (int ks = 0; ks < 2; ++ks)
            acc[0][i2][1][j2] =
                __builtin_amdgcn_mfma_f32_16x16x32_bf16(a[i2][ks], b1[j2][ks], acc[0][i2][1][j2], 0, 0, 0);
      __builtin_amdgcn_s_setprio(0);
    }

    // ---- phase 2 (even, no barrier): read a(h1); MFMA acc[1][*][0] ----
    {
#pragma unroll
      for (int i2 = 0; i2 < 4; ++i2)
#pragma unroll
        for (int ks = 0; ks < 2; ++ks) {
          const int byte = ((((wm * 4 + i2) * 16 + fr) * 128) + ks * 64 + fq * 16) ^ ((fr & 7) << 4);
          a[i2][ks] = *reinterpret_cast<const bf16x8*>(As1 + byte);
        }
      stage(j0 + 2);
      asm volatile("s_waitcnt vmcnt(6)" ::: "memory");
      __builtin_amdgcn_s_setprio(1);
#pragma unroll
      for (int i2 = 0; i2 < 4; ++i2)
#pragma unroll
        for (int j2 = 0; j2 < 2; ++j2)
#pragma unroll
          for (int ks = 0; ks < 2; ++ks)
            acc[1][i2][0][j2] =
                __builtin_amdgcn_mfma_f32_16x16x32_bf16(a[i2][ks], b0[j2][ks], acc[1][i2][0][j2], 0, 0, 0);
      __builtin_amdgcn_s_setprio(0);
    }

    // ---- phase 3 (odd, barrier): no reads; MFMA acc[1][*][1] ----
    {
      stage(j0 + 3);
      asm volatile("s_waitcnt vmcnt(6)" ::: "memory");
      asm volatile("s_barrier" ::: "memory");
      __builtin_amdgcn_s_setprio(1);
#pragma unroll
      for (int i2 = 0; i2 < 4; ++i2)
#pragma unroll
        for (int j2 = 0; j2 < 2; ++j2)
#pragma unroll
          for (int ks = 0; ks < 2; ++ks)
            acc[1][i2][1][j2] =
                __builtin_amdgcn_mfma_f32_16x16x32_bf16(a[i2][ks], b1[j2][ks], acc[1][i2][1][j2], 0, 0, 0);
      __builtin_amdgcn_s_setprio(0);
    }
  }

  asm volatile("s_waitcnt vmcnt(0)" ::: "memory");  // drain tail dummies

  // epilogue: C/D layout col = lane&15, row = (lane>>4)*4 + r
#pragma unroll
  for (int mh = 0; mh < 2; ++mh)
#pragma unroll
    for (int i2 = 0; i2 < 4; ++i2) {
      const int rbase = row0 + (mh * 8 + wm * 4 + i2) * 16 + fq * 4;
#pragma unroll
      for (int nh = 0; nh < 2; ++nh)
#pragma unroll
        for (int j2 = 0; j2 < 2; ++j2) {
          const int col = col0 + (nh * 8 + wn * 2 + j2) * 16 + fr;
#pragma unroll
          for (int r = 0; r < 4; ++r) {
            const float v = acc[mh][i2][nh][j2][r];
            const int row = rbase + r;
            if (EPI == 0) {
              const int seg = col >> 11, cc = col & 2047;
              unsigned short* dst = (seg == 0) ? Qo : (seg == 1 ? Ko : Vo);
              dst[(size_t)row * 2048 + cc] = f2bf(v);
            } else {
              Cf[(size_t)row * N + col] = v + bias[col];
            }
          }
        }
    }
}

// ========== attention diag + V scale v2: 256 t-rows per block, 8 waves ==========
// Grid 512: dispatch d -> head = d%64, tb = d/64  (all 8 blocks of a head land on
// XCD head%8 -> K-head stays L2-resident; 8 heads x 512 KB = 4 MB per XCD).
__global__ __launch_bounds__(512, 2)
void attn_diag_ov(const unsigned short* __restrict__ Q, const unsigned short* __restrict__ K,
                  const unsigned short* __restrict__ V, unsigned short* __restrict__ OV) {
  __shared__ __align__(16) char ks[2][128 * 256];  // 2 x 32 KB
  __shared__ float dlds[256];
  const int tid = threadIdx.x;
  const int lane = tid & 63, wid = tid >> 6;
  const int d = blockIdx.x;
  const int head = d & 63, tb = d >> 6;
  const int b = head >> 4, n = head & 15;
  const int t0 = tb << 8;
  const size_t hoff = (size_t)head << 18;  // head * 2048*128
  const unsigned short* Qh = Q + hoff;
  const unsigned short* Kh = K + hoff;
  const unsigned short* Vh = V + hoff;

  const int fr = lane & 15, fq = lane >> 4;
  const int g4 = fq << 2;
  const int qrow0 = t0 + wid * 32;

  // Q fragments direct from global: A-frag rows = Q rows, 4 k-chunks of 8 elems
  bf16x8 qf[2][4];
#pragma unroll
  for (int m = 0; m < 2; ++m)
#pragma unroll
    for (int kk = 0; kk < 4; ++kk)
      qf[m][kk] = *reinterpret_cast<const bf16x8*>(
          Qh + (size_t)(qrow0 + m * 16 + fr) * 128 + kk * 32 + fq * 8);

  // stage K-tile (128 rows x 128 cols bf16 = 32 KB) into buffer s; pre-swizzled source
  auto stageK = [&](int jc, int s) {
    const char* ksrc = (const char*)(Kh + ((size_t)jc << 7));
#pragma unroll
    for (int i = 0; i < 4; ++i) {
      const int flat = i * 8192 + tid * 16;
      const int row = flat >> 8, c = (flat >> 4) & 15;
      const int sb = (row << 8) + ((c ^ (row & 15)) << 4);
      gload_lds16(ksrc + sb, &ks[s][0] + flat);
    }
  };

  float rsum[2][4] = {};
  float dnum[2][4] = {};
  const float scale = 0.02209708691207961f;  // 1/sqrt(2048)

  stageK(0, 0);
  asm volatile("s_waitcnt vmcnt(0)" ::: "memory");
  asm volatile("s_barrier" ::: "memory");

  for (int t = 0; t < 16; ++t) {
    const int jc = t << 7;
    if (t < 15) stageK(jc + 128, (t + 1) & 1);
    const char* buf = &ks[t & 1][0];
#pragma unroll
    for (int jt = 0; jt < 8; ++jt) {
      bf16x8 bfrag[4];
#pragma unroll
      for (int kk = 0; kk < 4; ++kk) {
        const int row = jt * 16 + fr;
        const int s = kk * 4 + fq;
        bfrag[kk] = *reinterpret_cast<const bf16x8*>(buf + (row << 8) + ((s ^ (row & 15)) << 4));
      }
#pragma unroll
      for (int m = 0; m < 2; ++m) {
        f32x4 acc = {0.f, 0.f, 0.f, 0.f};
#pragma unroll
        for (int kk = 0; kk < 4; ++kk)
          acc = __builtin_amdgcn_mfma_f32_16x16x32_bf16(qf[m][kk], bfrag[kk], acc, 0, 0, 0);
        const int colj = jc + jt * 16 + fr;
        const int rowt = qrow0 + m * 16 + g4;
#pragma unroll
        for (int r = 0; r < 4; ++r) {
          const float e = __expf(acc[r] * scale);
          rsum[m][r] += e;
          if (colj == rowt + r) dnum[m][r] = e;
        }
      }
    }
    asm volatile("s_waitcnt vmcnt(0)" ::: "memory");
    asm volatile("s_barrier" ::: "memory");
  }

  // reduce across the 16 fr-lanes (xor 1,2,4,8 keeps fq bits intact)
#pragma unroll
  for (int m = 0; m < 2; ++m)
#pragma unroll
    for (int r = 0; r < 4; ++r) {
#pragma unroll
      for (int s = 1; s < 16; s <<= 1) {
        rsum[m][r] += __shfl_xor(rsum[m][r], s, 64);
        dnum[m][r] += __shfl_xor(dnum[m][r], s, 64);
      }
      if (fr == 0) dlds[wid * 32 + m * 16 + g4 + r] = dnum[m][r] / rsum[m][r];
    }
  __syncthreads();

  // OV write: rows t0..t0+255, cols n*128..+128 of OV (8192 x 2048)
  const unsigned short* vsrc = Vh + ((size_t)t0 << 7);
  unsigned short* dst = OV + ((size_t)((b << 11) + t0)) * 2048 + (n << 7);
#pragma unroll
  for (int c = 0; c < 8; ++c) {
    const int flat = (c * 512 + tid) << 3;
    const int row = flat >> 7, col = flat & 127;
    bf16x8 v = *reinterpret_cast<const bf16x8*>(vsrc + flat);
    const float dd = dlds[row];
    bf16x8 o;
#pragma unroll
    for (int e = 0; e < 8; ++e)
      o[e] = (short)f2bf(bf2f((unsigned short)v[e]) * dd);
    *reinterpret_cast<bf16x8*>(dst + (size_t)row * 2048 + col) = o;
  }
}

extern "C" void kernel_launch(void* const* d_in, const int* in_sizes, int n_in,
                              void* d_out, int out_size, void* d_ws, size_t ws_size,
                              hipStream_t stream) {
  const float* x = (const float*)d_in[0];        // (4,2048,2048)
  const float* w_qkv = (const float*)d_in[1];    // (2048,6144)
  const float* w_proj = (const float*)d_in[2];   // (2048,2048)
  const float* b_proj = (const float*)d_in[3];   // (2048,)
  float* out = (float*)d_out;                    // (4,2048,2048) f32

  char* p = (char*)d_ws;
  unsigned short* Xb = (unsigned short*)p;     p += (size_t)8192 * 2048 * 2;
  unsigned short* WqkvT = (unsigned short*)p;  p += (size_t)6144 * 2048 * 2;
  unsigned short* WprojT = (unsigned short*)p; p += (size_t)2048 * 2048 * 2;
  unsigned short* Qb = (unsigned short*)p;     p += (size_t)8192 * 2048 * 2;
  unsigned short* Kb = (unsigned short*)p;     p += (size_t)8192 * 2048 * 2;
  unsigned short* Vb = (unsigned short*)p;     p += (size_t)8192 * 2048 * 2;
  unsigned short* OV = (unsigned short*)p;     p += (size_t)8192 * 2048 * 2;

  // allow 128 KiB dynamic LDS (persistent function attribute; safe to repeat)
  (void)hipFuncSetAttribute((const void*)gemm256<0>,
                            hipFuncAttributeMaxDynamicSharedMemorySize, 131072);
  (void)hipFuncSetAttribute((const void*)gemm256<1>,
                            hipFuncAttributeMaxDynamicSharedMemorySize, 131072);

  cast_f32_bf16<<<16384, 256, 0, stream>>>(x, Xb);
  transpose_cast<<<dim3(192, 64), dim3(32, 8), 0, stream>>>(w_qkv, WqkvT, 2048, 6144);
  transpose_cast<<<dim3(64, 64), dim3(32, 8), 0, stream>>>(w_proj, WprojT, 2048, 2048);

  // QKV = Xb (8192x2048) * WqkvT^T -> split bf16 Q/K/V (B,T,D)
  gemm256<0><<<dim3(32 * 24), 512, 131072, stream>>>(Xb, WqkvT, Qb, Kb, Vb, nullptr, nullptr,
                                                     8192, 6144, 2048);
  // diag softmax + V scale -> OV (8192x2048) bf16
  attn_diag_ov<<<dim3(512), 512, 0, stream>>>(Qb, Kb, Vb, OV);
  // out = OV * WprojT^T + b_proj (f32)
  gemm256<1><<<dim3(32 * 8), 512, 131072, stream>>>(OV, WprojT, nullptr, nullptr, nullptr, out,
                                                    b_proj, 8192, 2048, 2048);
}